// Round 10
// baseline (928.968 us; speedup 1.0000x reference)
//
#include <hip/hip_runtime.h>
#include <cstddef>

#define NLEV 5
#define TOTROW 21330

typedef __bf16 bf16x8 __attribute__((ext_vector_type(8)));
typedef float f32x4 __attribute__((ext_vector_type(4)));
typedef unsigned short ushortx8 __attribute__((ext_vector_type(8)));

struct LvlP {
  int tileoff[6];
  int tilesX[5];
  int H[5], W[5];
  int roff[6];
  float inv8HW[5];
  float strd[5];
};

static __device__ __forceinline__ unsigned short f2bf(float f) {
  union { float f; unsigned u; } v; v.f = f;
  unsigned r = v.u + 0x7fffu + ((v.u >> 16) & 1u);
  return (unsigned short)(r >> 16);
}
static __device__ __forceinline__ float bf2f(unsigned short h) {
  union { unsigned u; float f; } v; v.u = ((unsigned)h) << 16;
  return v.f;
}
static __device__ __forceinline__ int sel5i(const int* a, int l) {
  int v = a[0];
  v = (l == 1) ? a[1] : v; v = (l == 2) ? a[2] : v;
  v = (l == 3) ? a[3] : v; v = (l == 4) ? a[4] : v;
  return v;
}
static __device__ __forceinline__ float sel5f(const float* a, int l) {
  float v = a[0];
  v = (l == 1) ? a[1] : v; v = (l == 2) ? a[2] : v;
  v = (l == 3) ? a[3] : v; v = (l == 4) ? a[4] : v;
  return v;
}

static __device__ __forceinline__ void gload16(const unsigned short* g, unsigned short* l) {
  __builtin_amdgcn_global_load_lds(
      (const __attribute__((address_space(1))) unsigned int*)(const void*)g,
      (__attribute__((address_space(3))) unsigned int*)(void*)l, 16, 0, 0);
}

// ---------------------------------------------------------------------------
// NCHW fp32 -> UNPADDED channel-last bf16: X[n][rbase + p][256]
// ---------------------------------------------------------------------------
__global__ __launch_bounds__(256) void to_chlast(
    const float* __restrict__ feat, unsigned short* __restrict__ X,
    int HW, int rbase)
{
  const int n = blockIdx.y >> 2, cb = blockIdx.y & 3;
  const int p0 = blockIdx.x * 64;
  __shared__ unsigned short s[64][72];
  const int t = threadIdx.x;
  const int pl = t & 63, ci = t >> 6;
  const float* src = feat + ((size_t)(n * 256 + cb * 64)) * HW;
#pragma unroll
  for (int i = 0; i < 16; ++i) {
    const int c = ci + i * 4;
    const int p = p0 + pl;
    float v = (p < HW) ? src[(size_t)c * HW + p] : 0.f;
    s[c][pl] = f2bf(v);
  }
  __syncthreads();
  const int cl = t & 63, pi = t >> 6;
#pragma unroll
  for (int i = 0; i < 16; ++i) {
    const int p = p0 + pi + i * 4;
    if (p < HW) {
      const size_t dst = ((size_t)n * TOTROW + rbase + p) * 256 + cb * 64 + cl;
      X[dst] = s[cl][pi + i * 4];
    }
  }
}

// ---------------------------------------------------------------------------
// tower weights fp32 [4][256][256][3][3] -> bf16 [layer][ch8][tap9][q4][oc256][8]
// ---------------------------------------------------------------------------
__global__ __launch_bounds__(256) void prep_tower_w(
    const float* __restrict__ cls_w, const float* __restrict__ box_w,
    unsigned short* __restrict__ wtC, unsigned short* __restrict__ wtR)
{
  const long e = (long)blockIdx.x * 256 + threadIdx.x;
  if (e >= 2359296L) return;
  const int j = (int)(e & 7);
  long r = e >> 3;
  const int oc = (int)(r & 255); r >>= 8;
  const int q = (int)(r & 3); r >>= 2;
  const int tap = (int)(r % 9);
  const long s = r / 9;
  const int ch = (int)(s & 7);
  const int layer = (int)(s >> 3);
  const int ic = ch * 32 + q * 8 + j;
  const long src = (((long)layer * 256 + oc) * 256 + ic) * 9 + tap;
  wtC[e] = f2bf(cls_w[src]);
  wtR[e] = f2bf(box_w[src]);
}

// ---------------------------------------------------------------------------
// head weights -> bf16 [ch16][tap9][q4][oc128][8]; also fills identity GN
// params for layer 0 (A=1, B=0).
// ---------------------------------------------------------------------------
__global__ __launch_bounds__(256) void prep_head_w(
    const float* __restrict__ sw, const float* __restrict__ sb,
    const float* __restrict__ cw, const float* __restrict__ cb,
    const float* __restrict__ pw, const float* __restrict__ pb,
    unsigned short* __restrict__ wth, float* __restrict__ bh,
    float* __restrict__ gnA0, float* __restrict__ gnB0)
{
  const long e = (long)blockIdx.x * 256 + threadIdx.x;
  if (e < 589824L) {
    const int j = (int)(e & 7);
    long r = e >> 3;
    const int oc = (int)(r & 127); r >>= 7;
    const int q = (int)(r & 3); r >>= 2;
    const int tap = (int)(r % 9);
    const int ch = (int)(r / 9);
    const int k = ch * 32 + q * 8 + j;
    float v = 0.f;
    if (oc < 80) { if (k < 256) v = sw[((long)(oc * 256 + k)) * 9 + tap]; }
    else if (oc == 80) { if (k >= 256) v = cw[(long)(k - 256) * 9 + tap]; }
    else if (oc < 85) { if (k >= 256) v = pw[((long)((oc - 81) * 256 + (k - 256))) * 9 + tap]; }
    wth[e] = f2bf(v);
  }
  if (e < 5120) { gnA0[e] = 1.f; gnB0[e] = 0.f; }
  if (blockIdx.x == 0) {
    const int t = threadIdx.x;
    if (t < 128) bh[t] = (t < 80) ? sb[t] : (t == 80) ? cb[0] : (t < 85) ? pb[t - 81] : 0.f;
  }
}

// ---------------------------------------------------------------------------
// GN affine params from stats: A = rs*gw, B = gb - m*rs*gw, per
// [level5][z4][ch256]. 5120 threads.
// ---------------------------------------------------------------------------
__global__ __launch_bounds__(256) void gnab_mk(
    const float* __restrict__ st,
    const float* __restrict__ gwC, const float* __restrict__ gbC,
    const float* __restrict__ gwR, const float* __restrict__ gbR,
    float* __restrict__ Aout, float* __restrict__ Bout, LvlP P)
{
  const int idx = blockIdx.x * 256 + threadIdx.x;
  if (idx >= 5120) return;
  const int c = idx & 255;
  const int z = (idx >> 8) & 3;
  const int l = idx >> 10;
  const int tower = z >> 1;
  const int g = c >> 3;
  const float* s = st + (((size_t)l * 4 + z) * 32 + g) * 2;
  const float inv = sel5f(P.inv8HW, l);
  const float m = s[0] * inv;
  const float var = s[1] * inv - m * m;
  const float rs = rsqrtf(var + 1e-5f);
  const float gw = (tower ? gwR : gwC)[c];
  const float gb = (tower ? gbR : gbC)[c];
  Aout[idx] = rs * gw;
  Bout[idx] = gb - m * rs * gw;
}

// ---------------------------------------------------------------------------
// MFMA implicit-GEMM 3x3 conv with FUSED input GN+ReLU, all levels in one
// dispatch. R9 structure (XCD-cohort swizzle, sB gload_lds, 2 barriers/chunk,
// af[2][5] dedup, 2 blocks/CU) with the A-staging switched to reg-staging:
// load 16B (8 ch = 1 GN group) -> y = x*A[c]+B[c] (+ReLU if dorelu) in f32
// -> bf16 -> ds_write_b128. Border zeros via per-item validity mask (no
// padded buffers, no gn_apply kernel, no memsets). part = lane&3 is fixed
// per lane -> 8 A + 8 B params per lane per chunk (L1-hot 40 KB table).
// kimg=1: towers, z=tower*2+n, ny=4. kimg=2: head SPLIT-K, z=half*2+n,
// ny=2, weight rows 8-15 for the box half; Yh slices disjoint.
// ---------------------------------------------------------------------------
__global__ __launch_bounds__(256, 2) void conv_mfma(
    const unsigned short* __restrict__ inC, const unsigned short* __restrict__ inR,
    unsigned short* __restrict__ outC, unsigned short* __restrict__ outR,
    const unsigned short* __restrict__ wtC, const unsigned short* __restrict__ wtR,
    const float* __restrict__ bsC, const float* __restrict__ bsR,
    float* __restrict__ stats, const float* __restrict__ gnA,
    const float* __restrict__ gnB, int dorelu, LvlP P, int kimg, int octot)
{
  // ---- XCD-cohort remap: ny oc0-blocks of one (tile,z) land on one XCD;
  //      z is constant per XCD -> one image + one weight set per XCD L2.
  const int ny = (kimg == 1) ? 4 : 2;
  const int nz = 4;
  const int span = ny * 8;
  const int total = 69 * ny * nz;
  const int SG = total / span;
  const int braw = blockIdx.x;
  int j, yy;
  if (braw < SG * span) {
    j = (braw / span) * 8 + (braw & 7);
    yy = (braw % span) >> 3;
  } else {
    const int p = braw - SG * span;
    const int cpx = (total - SG * span) / ny;
    j = SG * 8 + p % cpx;
    yy = p / cpx;
  }
  const int z = j % nz;
  const int bt = j / nz;                // tile index 0..68
  const int oc0 = yy << 6;

  const int l = (bt >= P.tileoff[1]) + (bt >= P.tileoff[2])
              + (bt >= P.tileoff[3]) + (bt >= P.tileoff[4]);
  const int t = bt - sel5i(P.tileoff, l);
  const int tX = sel5i(P.tilesX, l);
  const int ty = t / tX, tx = t - ty * tX;
  const int x0 = tx << 5, y0 = ty * 12;
  const int H = sel5i(P.H, l), W = sel5i(P.W, l);
  const int rbase = sel5i(P.roff, l);

  const unsigned short *Ain, *wt;
  const float* bs; unsigned short* out;
  int wchoff = 0;
  if (kimg == 1) {
    const int tower = z >> 1, n = z & 1;
    Ain = (tower ? inR : inC) + (size_t)n * TOTROW * 256;
    wt = tower ? wtR : wtC;
    bs = tower ? bsR : bsC;
    out = (tower ? outR : outC) + (size_t)n * TOTROW * octot;
  } else {
    const int half = z >> 1, n = z & 1;
    Ain = (half ? inR : inC) + (size_t)n * TOTROW * 256;
    wt = wtC; bs = bsC;
    wchoff = half * 8;
    out = outC + (size_t)z * TOTROW * octot;
  }

  __shared__ unsigned short sA[512 * 32];   // [pos 476(+pad)][part4][8ic]  32 KB
  __shared__ unsigned short sB[36 * 512];   // [tap][q][oc64][8ic]          36 KB

  const int tid = threadIdx.x;
  const int wv = tid >> 6, lane = tid & 63;
  const int t15 = lane & 15, q = lane >> 4;

  // per-lane A-staging source offsets (shorts, unpadded Y) + validity mask
  unsigned aoff[8]; unsigned vmask = 0;
#pragma unroll
  for (int it = 0; it < 8; ++it) {
    const int inst = wv + it * 4;
    const int item = (inst << 6) + lane;
    int pos = item >> 2; pos = (pos > 475) ? 475 : pos;
    const int part = item & 3;
    const int hy = pos / 34, hx = pos - hy * 34;
    const int gy = y0 + hy - 1, gx = x0 + hx - 1;
    const int val = (gy >= 0 && gy < H && gx >= 0 && gx < W) ? 1 : 0;
    const int ridx = val ? (rbase + gy * W + gx) : rbase;
    aoff[it] = ((unsigned)ridx << 8) + (part << 3);
    vmask |= (unsigned)val << it;
  }

  f32x4 acc[6][4];
#pragma unroll
  for (int g = 0; g < 4; ++g) {
    const float b = bs[oc0 + g * 16 + t15];
#pragma unroll
    for (int f = 0; f < 6; ++f) {
      acc[f][g][0] = b; acc[f][g][1] = b; acc[f][g][2] = b; acc[f][g][3] = b;
    }
  }

  const float* gnAl = gnA + (((size_t)(l * 4 + z)) << 8) + ((lane & 3) << 3);
  const float* gnBl = gnB + (((size_t)(l * 4 + z)) << 8) + ((lane & 3) << 3);

  for (int ch = 0; ch < 8; ++ch) {
    const unsigned icb = (unsigned)ch << 5;
    // GN params for this lane's 8 channels (part fixed = lane&3)
    float a8[8], b8[8];
#pragma unroll
    for (int jj = 0; jj < 8; ++jj) { a8[jj] = gnAl[icb + jj]; b8[jj] = gnBl[icb + jj]; }
    // reg-stage A: load 16B, apply GN(+ReLU), mask borders to zero
    ushortx8 w[8];
#pragma unroll
    for (int it = 0; it < 8; ++it) {
      const ushortx8 dv = *(const ushortx8*)(Ain + aoff[it] + icb);
      const int val = (vmask >> it) & 1;
#pragma unroll
      for (int jj = 0; jj < 8; ++jj) {
        const float x = bf2f(dv[jj]);
        float y = x * a8[jj] + b8[jj];
        y = dorelu ? fmaxf(y, 0.f) : y;
        w[it][jj] = val ? f2bf(y) : (unsigned short)0;
      }
    }
    __syncthreads();                       // all reads of prev chunk done
#pragma unroll
    for (int it = 0; it < 8; ++it)
      *(ushortx8*)(sA + ((wv + it * 4) << 9) + (lane << 3)) = w[it];
    // B stage: 36 wave-instructions, fully contiguous 1 KB each
    const unsigned short* wb = wt + ((size_t)((ch + wchoff) * 36) * octot + oc0) * 8 + (lane << 3);
#pragma unroll
    for (int it = 0; it < 9; ++it)
      gload16(wb + (size_t)(wv + it * 4) * octot * 8, sB + ((wv + it * 4) << 9));
    __syncthreads();                       // ds_writes + B loads landed

#pragma unroll
    for (int kx = 0; kx < 3; ++kx) {
      // hoist the 5 distinct A rows (x 2 col-halves) for this kx
      bf16x8 af[2][5];
#pragma unroll
      for (int fc = 0; fc < 2; ++fc)
#pragma unroll
        for (int r = 0; r < 5; ++r) {
          const int pos = (wv * 3 + r) * 34 + fc * 16 + t15 + kx;
          af[fc][r] = *(const bf16x8*)(sA + ((pos * 4 + q) << 3));
        }
#pragma unroll
      for (int ky = 0; ky < 3; ++ky) {
        const int tap = ky * 3 + kx;
        bf16x8 b[4];
#pragma unroll
        for (int g = 0; g < 4; ++g)
          b[g] = *(const bf16x8*)(sB + ((((tap * 4 + q) << 6) + g * 16 + t15) << 3));
#pragma unroll
        for (int fr = 0; fr < 3; ++fr)
#pragma unroll
          for (int fc = 0; fc < 2; ++fc) {
            const bf16x8 a = af[fc][fr + ky];
#pragma unroll
            for (int g = 0; g < 4; ++g)
              acc[fr * 2 + fc][g] =
                  __builtin_amdgcn_mfma_f32_16x16x32_bf16(a, b[g], acc[fr * 2 + fc][g], 0, 0, 0);
          }
      }
    }
  }

  // epilogue: store raw bf16 + fused GN partial stats
#pragma unroll
  for (int g = 0; g < 4; ++g) {
    const int oc = oc0 + g * 16 + t15;
    float s = 0.f, ss = 0.f;
#pragma unroll
    for (int f = 0; f < 6; ++f) {
      const int fr = f >> 1, fc = f & 1;
      const int gy = y0 + wv * 3 + fr;
#pragma unroll
      for (int rg = 0; rg < 4; ++rg) {
        const int gx = x0 + fc * 16 + q * 4 + rg;
        if (gy < H && gx < W) {
          const float v = acc[f][g][rg];
          out[(size_t)(rbase + gy * W + gx) * octot + oc] = f2bf(v);
          s += v; ss += v * v;
        }
      }
    }
    if (stats) {
      s += __shfl_xor(s, 1);  ss += __shfl_xor(ss, 1);
      s += __shfl_xor(s, 2);  ss += __shfl_xor(ss, 2);
      s += __shfl_xor(s, 4);  ss += __shfl_xor(ss, 4);
      s += __shfl_xor(s, 16); ss += __shfl_xor(ss, 16);
      if ((lane & 55) == 0) {   // lanes 0 and 8 hold the two GN groups of this g
        float* st = stats + (((size_t)l * 4 + z) * 32 + (oc >> 3)) * 2;
        atomicAdd(st, s); atomicAdd(st + 1, ss);
      }
    }
  }
}

// ---------------------------------------------------------------------------
// Head epilogue, merged levels. Split-K Yh: slice n (half=0) has score
// logits; slice 2+n (half=1) has ctr/pred.
// ---------------------------------------------------------------------------
__global__ __launch_bounds__(256) void head_epi(
    const unsigned short* __restrict__ Yh, float* __restrict__ out,
    const float* __restrict__ scales, LvlP P)
{
  const int n = blockIdx.y;
  const int e = blockIdx.x * 256 + threadIdx.x;
  if (e >= TOTROW * 84) return;
  const int pos = e / 84;
  const int j = e - pos * 84;
  const int l = (pos >= P.roff[1]) + (pos >= P.roff[2]) + (pos >= P.roff[3]) + (pos >= P.roff[4]);
  const unsigned short* yc_ = Yh + ((size_t)n * TOTROW + pos) * 128;
  const unsigned short* yb_ = Yh + ((size_t)(2 + n) * TOTROW + pos) * 128;
  float v;
  if (j < 80) {
    const float lg = bf2f(yc_[j]);
    const float ct = bf2f(yb_[80]);
    v = (1.f / (1.f + __expf(-lg))) * (1.f / (1.f + __expf(-ct)));
  } else {
    const int d = j - 80;
    const float stride = sel5f(P.strd, l);
    const int W = sel5i(P.W, l);
    const int local = pos - sel5i(P.roff, l);
    const int gy = local / W, gx = local - gy * W;
    const float pv = bf2f(yb_[81 + d]);
    const float rg = fmaxf(pv * scales[l], 0.f) * stride;
    const float sx = gx * stride, sy = gy * stride;
    v = (d == 0) ? sx - rg : (d == 1) ? sy - rg : (d == 2) ? sx + rg : sy + rg;
  }
  out[((size_t)n * TOTROW + pos) * 84 + j] = v;
}

// ---------------------------------------------------------------------------
extern "C" void kernel_launch(void* const* d_in, const int* in_sizes, int n_in,
                              void* d_out, int out_size, void* d_ws, size_t ws_size,
                              hipStream_t stream)
{
  (void)in_sizes; (void)n_in; (void)out_size; (void)ws_size;

  const float* feats[5];
  for (int l = 0; l < 5; ++l) feats[l] = (const float*)d_in[l];
  const float* cls_w  = (const float*)d_in[5];
  const float* cls_b  = (const float*)d_in[6];
  const float* cls_gw = (const float*)d_in[7];
  const float* cls_gb = (const float*)d_in[8];
  const float* box_w  = (const float*)d_in[9];
  const float* box_b  = (const float*)d_in[10];
  const float* box_gw = (const float*)d_in[11];
  const float* box_gb = (const float*)d_in[12];
  const float* score_w = (const float*)d_in[13];
  const float* score_b = (const float*)d_in[14];
  const float* pred_w  = (const float*)d_in[15];
  const float* pred_b  = (const float*)d_in[16];
  const float* ctr_w   = (const float*)d_in[17];
  const float* ctr_b   = (const float*)d_in[18];
  const float* scales  = (const float*)d_in[19];
  float* out = (float*)d_out;

  static const int Hs[5] = {100, 50, 25, 13, 7};
  static const int Ws[5] = {160, 80, 40, 20, 10};
  LvlP P;
  {
    static const int to[6] = {0, 45, 60, 66, 68, 69};   // 32x12 tiles
    static const int tX[5] = {5, 3, 2, 1, 1};
    static const int ro[6] = {0, 16000, 20000, 21000, 21260, 21330};
    for (int i = 0; i < 6; ++i) { P.tileoff[i] = to[i]; P.roff[i] = ro[i]; }
    for (int i = 0; i < 5; ++i) {
      P.tilesX[i] = tX[i]; P.H[i] = Hs[i]; P.W[i] = Ws[i];
      P.inv8HW[i] = 1.f / (8.f * Hs[i] * Ws[i]);
      P.strd[i] = (float)(8 << i);
    }
  }

  char* p = (char*)d_ws;
  auto alloc = [&](size_t bytes) {
    char* r = p;
    p += (bytes + 255) & ~(size_t)255;
    return r;
  };
  const size_t YSZ = (size_t)2 * TOTROW * 256 * 2;
  unsigned short* Xf  = (unsigned short*)alloc(YSZ);
  unsigned short* Yc0 = (unsigned short*)alloc(YSZ);
  unsigned short* Yr0 = (unsigned short*)alloc(YSZ);
  unsigned short* Yc1 = (unsigned short*)alloc(YSZ);
  unsigned short* Yr1 = (unsigned short*)alloc(YSZ);
  unsigned short* Yh  = (unsigned short*)alloc((size_t)4 * TOTROW * 128 * 2);
  unsigned short* wtC = (unsigned short*)alloc(4718592);
  unsigned short* wtR = (unsigned short*)alloc(4718592);
  unsigned short* wth = (unsigned short*)alloc(1179648);
  float* bh    = (float*)alloc(512);
  float* stats = (float*)alloc(4 * 5 * 4 * 32 * 2 * sizeof(float));
  float* gnA   = (float*)alloc(5 * 5120 * sizeof(float));
  float* gnB   = (float*)alloc(5 * 5120 * sizeof(float));

  hipMemsetAsync(stats, 0, 4 * 5 * 4 * 32 * 2 * sizeof(float), stream);

  prep_tower_w<<<9216, 256, 0, stream>>>(cls_w, box_w, wtC, wtR);
  prep_head_w<<<2304, 256, 0, stream>>>(score_w, score_b, ctr_w, ctr_b,
                                        pred_w, pred_b, wth, bh, gnA, gnB);
  for (int l = 0; l < 5; ++l) {
    const int HW = Hs[l] * Ws[l];
    to_chlast<<<dim3((HW + 63) / 64, 8), 256, 0, stream>>>(
        feats[l], Xf, HW, P.roff[l]);
  }

  const unsigned short* pc = Xf;
  const unsigned short* pr = Xf;
  for (int i = 0; i < 4; ++i) {
    unsigned short* qc = (i & 1) ? Yc1 : Yc0;
    unsigned short* qr = (i & 1) ? Yr1 : Yr0;
    float* st = stats + (size_t)i * 5 * 4 * 32 * 2;
    conv_mfma<<<dim3(1104), 256, 0, stream>>>(
        pc, pr, qc, qr,
        wtC + (size_t)i * 589824, wtR + (size_t)i * 589824,
        cls_b + i * 256, box_b + i * 256, st,
        gnA + (size_t)i * 5120, gnB + (size_t)i * 5120, (i > 0) ? 1 : 0,
        P, 1, 256);
    gnab_mk<<<20, 256, 0, stream>>>(
        st, cls_gw + i * 256, cls_gb + i * 256,
        box_gw + i * 256, box_gb + i * 256,
        gnA + (size_t)(i + 1) * 5120, gnB + (size_t)(i + 1) * 5120, P);
    pc = qc; pr = qr;
  }

  conv_mfma<<<dim3(552), 256, 0, stream>>>(
      pc, pr, Yh, nullptr, wth, nullptr, bh, nullptr, nullptr,
      gnA + (size_t)4 * 5120, gnB + (size_t)4 * 5120, 1, P, 2, 128);
  head_epi<<<dim3((TOTROW * 84 + 255) / 256, 2), 256, 0, stream>>>(
      Yh, out, scales, P);
}

// Round 11
// 781.724 us; speedup vs baseline: 1.1884x; 1.1884x over previous
//
#include <hip/hip_runtime.h>
#include <cstddef>

#define NLEV 5
#define TOTROW 21330
#define PTOT 22360   // sum of (H+2)*(W+2)

typedef __bf16 bf16x8 __attribute__((ext_vector_type(8)));
typedef float f32x4 __attribute__((ext_vector_type(4)));
typedef unsigned short ushortx8 __attribute__((ext_vector_type(8)));

struct LvlP {
  int tileoff[6];
  int tilesX[5];
  int H[5], W[5];
  int poff[5], pend[5];
  int roff[6];
  float inv8HW[5];
  float strd[5];
};

struct FPtrs { const float* f[5]; };

static __device__ __forceinline__ unsigned short f2bf(float f) {
  union { float f; unsigned u; } v; v.f = f;
  unsigned r = v.u + 0x7fffu + ((v.u >> 16) & 1u);
  return (unsigned short)(r >> 16);
}
static __device__ __forceinline__ float bf2f(unsigned short h) {
  union { unsigned u; float f; } v; v.u = ((unsigned)h) << 16;
  return v.f;
}
static __device__ __forceinline__ int sel5i(const int* a, int l) {
  int v = a[0];
  v = (l == 1) ? a[1] : v; v = (l == 2) ? a[2] : v;
  v = (l == 3) ? a[3] : v; v = (l == 4) ? a[4] : v;
  return v;
}
static __device__ __forceinline__ float sel5f(const float* a, int l) {
  float v = a[0];
  v = (l == 1) ? a[1] : v; v = (l == 2) ? a[2] : v;
  v = (l == 3) ? a[3] : v; v = (l == 4) ? a[4] : v;
  return v;
}

static __device__ __forceinline__ void gload16(const unsigned short* g, unsigned short* l) {
  __builtin_amdgcn_global_load_lds(
      (const __attribute__((address_space(1))) unsigned int*)(const void*)g,
      (__attribute__((address_space(3))) unsigned int*)(void*)l, 16, 0, 0);
}

// ---------------------------------------------------------------------------
// NCHW fp32 -> padded channel-last bf16, ALL levels in one dispatch.
// Per-level 64-pos blocks; compile-time block offsets {0,250,313,329,334,336}.
// grid (336, 8): y = n*4 + cb.
// ---------------------------------------------------------------------------
__global__ __launch_bounds__(256) void to_chlast_all(
    FPtrs F, unsigned short* __restrict__ X, LvlP P)
{
  const int bx = blockIdx.x;
  const int l = (bx >= 250) + (bx >= 313) + (bx >= 329) + (bx >= 334);
  const int boff[5] = {0, 250, 313, 329, 334};
  const int b0 = sel5i(boff, l);
  const int H = sel5i(P.H, l), W = sel5i(P.W, l);
  const int HW = H * W;
  const int poff = sel5i(P.poff, l);
  const float* feat = F.f[l];

  const int n = blockIdx.y >> 2, cb = blockIdx.y & 3;
  const int p0 = (bx - b0) * 64;
  __shared__ unsigned short s[64][72];
  const int t = threadIdx.x;
  const int pl = t & 63, ci = t >> 6;
  const float* src = feat + ((size_t)(n * 256 + cb * 64)) * HW;
#pragma unroll
  for (int i = 0; i < 16; ++i) {
    const int c = ci + i * 4;
    const int p = p0 + pl;
    float v = (p < HW) ? src[(size_t)c * HW + p] : 0.f;
    s[c][pl] = f2bf(v);
  }
  __syncthreads();
  const int cl = t & 63, pi = t >> 6;
#pragma unroll
  for (int i = 0; i < 16; ++i) {
    const int p = p0 + pi + i * 4;
    if (p < HW) {
      const int y = p / W, x = p - y * W;
      const size_t dst = ((size_t)n * PTOT + poff + (y + 1) * (W + 2) + (x + 1)) * 256
                       + cb * 64 + cl;
      X[dst] = s[cl][pi + i * 4];
    }
  }
}

// ---------------------------------------------------------------------------
// Merged weight prep (tower + head) in one dispatch.
// blocks [0, 9216): tower weights fp32 [4][256][256][3][3] ->
//   bf16 [layer][ch8][tap9][q4][oc256][8].
// blocks [9216, 11520): head weights -> bf16 [ch16][tap9][q4][oc128][8];
//   k = ch*32+q*8+j in [0,512): k<256 cls-input (score), k>=256 box-input.
// ---------------------------------------------------------------------------
__global__ __launch_bounds__(256) void prep_w(
    const float* __restrict__ cls_w, const float* __restrict__ box_w,
    unsigned short* __restrict__ wtC, unsigned short* __restrict__ wtR,
    const float* __restrict__ sw, const float* __restrict__ sb,
    const float* __restrict__ cw, const float* __restrict__ cbias,
    const float* __restrict__ pw, const float* __restrict__ pb,
    unsigned short* __restrict__ wth, float* __restrict__ bh)
{
  if (blockIdx.x < 9216) {
    const long e = (long)blockIdx.x * 256 + threadIdx.x;
    if (e >= 2359296L) return;
    const int j = (int)(e & 7);
    long r = e >> 3;
    const int oc = (int)(r & 255); r >>= 8;
    const int q = (int)(r & 3); r >>= 2;
    const int tap = (int)(r % 9);
    const long s = r / 9;
    const int ch = (int)(s & 7);
    const int layer = (int)(s >> 3);
    const int ic = ch * 32 + q * 8 + j;
    const long src = (((long)layer * 256 + oc) * 256 + ic) * 9 + tap;
    wtC[e] = f2bf(cls_w[src]);
    wtR[e] = f2bf(box_w[src]);
  } else {
    const long e = (long)(blockIdx.x - 9216) * 256 + threadIdx.x;
    if (e < 589824L) {
      const int j = (int)(e & 7);
      long r = e >> 3;
      const int oc = (int)(r & 127); r >>= 7;
      const int q = (int)(r & 3); r >>= 2;
      const int tap = (int)(r % 9);
      const int ch = (int)(r / 9);
      const int k = ch * 32 + q * 8 + j;
      float v = 0.f;
      if (oc < 80) { if (k < 256) v = sw[((long)(oc * 256 + k)) * 9 + tap]; }
      else if (oc == 80) { if (k >= 256) v = cw[(long)(k - 256) * 9 + tap]; }
      else if (oc < 85) { if (k >= 256) v = pw[((long)((oc - 81) * 256 + (k - 256))) * 9 + tap]; }
      wth[e] = f2bf(v);
    }
    if (blockIdx.x == 9216) {
      const int t = threadIdx.x;
      if (t < 128) bh[t] = (t < 80) ? sb[t] : (t == 80) ? cbias[0] : (t < 85) ? pb[t - 81] : 0.f;
    }
  }
}

// ---------------------------------------------------------------------------
// MFMA implicit-GEMM 3x3 conv, all levels in one dispatch. R9 structure
// (proven best, 821 us total): A+B staged to LDS via global_load_lds,
// single-buffered, 2 barriers per 32-ic chunk, LDS 68 KB, af[2][5] A-dedup,
// XCD-cohort swizzle (FETCH 144->39 MB). Occupancy is structurally 2
// blocks/CU: unified regfile = arch VGPR (~112) + acc AGPR (96) ~= 208
// -> 2 waves/EU regardless of LDS (R8); B-direct-from-global (R8),
// launch_bounds>2 (R4/R7), dbuf pipelines (R1/R2), and GN-fusion into
// staging (R10: reg-staging VALU cost) all regress.
// kimg=1: towers, z=tower*2+n, ny=4, K=256 (8 chunks).
// kimg=2: head SPLIT-K, z=half*2+n, ny=2: half=0 -> score logits from
// cls-X (weight rows 0-7); half=1 -> ctr/pred from box-X (rows 8-15).
// Each writes its own Yh slice; contributions disjoint; both carry bias.
// ---------------------------------------------------------------------------
__global__ __launch_bounds__(256, 2) void conv_mfma(
    const unsigned short* __restrict__ inC, const unsigned short* __restrict__ inR,
    unsigned short* __restrict__ outC, unsigned short* __restrict__ outR,
    const unsigned short* __restrict__ wtC, const unsigned short* __restrict__ wtR,
    const float* __restrict__ bsC, const float* __restrict__ bsR,
    float* __restrict__ stats, LvlP P, int kimg, int octot)
{
  // ---- XCD-cohort remap: ny oc0-blocks of one (tile,z) land on one XCD;
  //      z is constant per XCD -> one image + one weight set per XCD L2.
  const int ny = (kimg == 1) ? 4 : 2;   // oc0 blocks per (tile,z)
  const int nz = 4;
  const int span = ny * 8;
  const int total = 69 * ny * nz;
  const int SG = total / span;
  const int braw = blockIdx.x;
  int j, yy;
  if (braw < SG * span) {
    j = (braw / span) * 8 + (braw & 7);
    yy = (braw % span) >> 3;
  } else {
    const int p = braw - SG * span;
    const int cpx = (total - SG * span) / ny;
    j = SG * 8 + p % cpx;
    yy = p / cpx;
  }
  const int z = j % nz;
  const int bt = j / nz;                // tile index 0..68
  const int oc0 = yy << 6;

  const int l = (bt >= P.tileoff[1]) + (bt >= P.tileoff[2])
              + (bt >= P.tileoff[3]) + (bt >= P.tileoff[4]);
  const int t = bt - sel5i(P.tileoff, l);
  const int tX = sel5i(P.tilesX, l);
  const int ty = t / tX, tx = t - ty * tX;
  const int x0 = tx << 5, y0 = ty * 12;
  const int H = sel5i(P.H, l), W = sel5i(P.W, l);
  const int W2 = W + 2;
  const int pbase = sel5i(P.poff, l);
  const int pmax = sel5i(P.pend, l) - 1;
  const int rbase = sel5i(P.roff, l);

  const unsigned short *A, *wt;
  const float* bs; unsigned short* out;
  int wchoff = 0;
  if (kimg == 1) {
    const int tower = z >> 1, n = z & 1;
    A = (tower ? inR : inC) + (size_t)n * PTOT * 256;
    wt = tower ? wtR : wtC;
    bs = tower ? bsR : bsC;
    out = (tower ? outR : outC) + (size_t)n * TOTROW * octot;
  } else {
    const int half = z >> 1, n = z & 1;
    A = (half ? inR : inC) + (size_t)n * PTOT * 256;
    wt = wtC; bs = bsC;
    wchoff = half * 8;                  // weight rows 8-15 for the box half
    out = outC + (size_t)z * TOTROW * octot;   // Yh slice [half*2+n]
  }

  __shared__ unsigned short sA[512 * 32];   // [pos 476(+pad)][part4][8ic]  32 KB
  __shared__ unsigned short sB[36 * 512];   // [tap][q][oc64][8ic]          36 KB

  const int tid = threadIdx.x;
  const int wv = tid >> 6, lane = tid & 63;
  const int t15 = lane & 15, q = lane >> 4;

  // per-lane A-staging source offsets (in shorts): 8 instrs/wave, 32 total
  unsigned aoff[8];
#pragma unroll
  for (int it = 0; it < 8; ++it) {
    const int inst = wv + it * 4;
    const int item = (inst << 6) + lane;
    int pos = item >> 2; pos = (pos > 475) ? 475 : pos;
    const int part = item & 3;
    const int hy = pos / 34, hx = pos - hy * 34;
    int pidx = pbase + (y0 + hy) * W2 + (x0 + hx);
    pidx = (pidx > pmax) ? pmax : pidx;
    aoff[it] = ((unsigned)pidx << 8) + (part << 3);
  }

  f32x4 acc[6][4];
#pragma unroll
  for (int g = 0; g < 4; ++g) {
    const float b = bs[oc0 + g * 16 + t15];
#pragma unroll
    for (int f = 0; f < 6; ++f) {
      acc[f][g][0] = b; acc[f][g][1] = b; acc[f][g][2] = b; acc[f][g][3] = b;
    }
  }

  for (int ch = 0; ch < 8; ++ch) {
    const unsigned icb = (unsigned)ch << 5;
    __syncthreads();
    // A stage: 32 wave-instructions of 64 lanes x 16 B
#pragma unroll
    for (int it = 0; it < 8; ++it)
      gload16(A + aoff[it] + icb, sA + ((wv + it * 4) << 9));
    // B stage: 36 wave-instructions, fully contiguous 1 KB each
    const unsigned short* wb = wt + ((size_t)((ch + wchoff) * 36) * octot + oc0) * 8 + (lane << 3);
#pragma unroll
    for (int it = 0; it < 9; ++it)
      gload16(wb + (size_t)(wv + it * 4) * octot * 8, sB + ((wv + it * 4) << 9));
    __syncthreads();

#pragma unroll
    for (int kx = 0; kx < 3; ++kx) {
      // hoist the 5 distinct A rows (x 2 col-halves) for this kx
      bf16x8 af[2][5];
#pragma unroll
      for (int fc = 0; fc < 2; ++fc)
#pragma unroll
        for (int r = 0; r < 5; ++r) {
          const int pos = (wv * 3 + r) * 34 + fc * 16 + t15 + kx;
          af[fc][r] = *(const bf16x8*)(sA + ((pos * 4 + q) << 3));
        }
#pragma unroll
      for (int ky = 0; ky < 3; ++ky) {
        const int tap = ky * 3 + kx;
        bf16x8 b[4];
#pragma unroll
        for (int g = 0; g < 4; ++g)
          b[g] = *(const bf16x8*)(sB + ((((tap * 4 + q) << 6) + g * 16 + t15) << 3));
#pragma unroll
        for (int fr = 0; fr < 3; ++fr)
#pragma unroll
          for (int fc = 0; fc < 2; ++fc) {
            const bf16x8 a = af[fc][fr + ky];
#pragma unroll
            for (int g = 0; g < 4; ++g)
              acc[fr * 2 + fc][g] =
                  __builtin_amdgcn_mfma_f32_16x16x32_bf16(a, b[g], acc[fr * 2 + fc][g], 0, 0, 0);
          }
      }
    }
  }

  // epilogue: store bf16 + fused GN partial stats
#pragma unroll
  for (int g = 0; g < 4; ++g) {
    const int oc = oc0 + g * 16 + t15;
    float s = 0.f, ss = 0.f;
#pragma unroll
    for (int f = 0; f < 6; ++f) {
      const int fr = f >> 1, fc = f & 1;
      const int gy = y0 + wv * 3 + fr;
#pragma unroll
      for (int rg = 0; rg < 4; ++rg) {
        const int gx = x0 + fc * 16 + q * 4 + rg;
        if (gy < H && gx < W) {
          const float v = acc[f][g][rg];
          out[(size_t)(rbase + gy * W + gx) * octot + oc] = f2bf(v);
          s += v; ss += v * v;
        }
      }
    }
    if (stats) {
      s += __shfl_xor(s, 1);  ss += __shfl_xor(ss, 1);
      s += __shfl_xor(s, 2);  ss += __shfl_xor(ss, 2);
      s += __shfl_xor(s, 4);  ss += __shfl_xor(ss, 4);
      s += __shfl_xor(s, 16); ss += __shfl_xor(ss, 16);
      if ((lane & 55) == 0) {   // lanes 0 and 8 hold the two GN groups of this g
        float* st = stats + (((size_t)l * 4 + z) * 32 + (oc >> 3)) * 2;
        atomicAdd(st, s); atomicAdd(st + 1, ss);
      }
    }
  }
}

// ---------------------------------------------------------------------------
// GN apply + ReLU, merged levels: reads unpadded Y, writes padded X interior.
// grid: (ceil(21330*32/256), 4 imgs)
// ---------------------------------------------------------------------------
__global__ __launch_bounds__(256) void gn_apply(
    const unsigned short* __restrict__ Yc, const unsigned short* __restrict__ Yr,
    unsigned short* __restrict__ Xc, unsigned short* __restrict__ Xr,
    const float* __restrict__ stats,
    const float* __restrict__ gwC, const float* __restrict__ gbC,
    const float* __restrict__ gwR, const float* __restrict__ gbR, LvlP P)
{
  const int img = blockIdx.y;
  const int tower = img >> 1, n = img & 1;
  const int e = blockIdx.x * 256 + threadIdx.x;
  const int pos = e >> 5;
  const int g = e & 31;
  if (pos >= TOTROW) return;
  const int l = (pos >= P.roff[1]) + (pos >= P.roff[2]) + (pos >= P.roff[3]) + (pos >= P.roff[4]);
  const int W = sel5i(P.W, l);
  const int local = pos - sel5i(P.roff, l);
  const int y = local / W, x = local - y * W;
  const size_t dst = ((size_t)n * PTOT + sel5i(P.poff, l) + (y + 1) * (W + 2) + (x + 1)) * 256 + g * 8;
  const size_t srco = ((size_t)n * TOTROW + pos) * 256 + g * 8;
  const unsigned short* Y = (tower ? Yr : Yc) + srco;
  unsigned short* X = (tower ? Xr : Xc) + dst;
  const float* gw = (tower ? gwR : gwC) + g * 8;
  const float* gb = (tower ? gbR : gbC) + g * 8;
  const float* st = stats + (((size_t)l * 4 + img) * 32 + g) * 2;
  const float inv = sel5f(P.inv8HW, l);
  const float m = st[0] * inv;
  const float var = st[1] * inv - m * m;
  const float rs = rsqrtf(var + 1e-5f);
  ushortx8 yv = *(const ushortx8*)Y;
  ushortx8 xv;
#pragma unroll
  for (int j = 0; j < 8; ++j) {
    const float yj = bf2f(yv[j]);
    const float v = (yj - m) * rs * gw[j] + gb[j];
    xv[j] = f2bf(fmaxf(v, 0.f));
  }
  *(ushortx8*)X = xv;
}

// ---------------------------------------------------------------------------
// Head epilogue, merged levels. Split-K Yh: slice n (half=0) has score
// logits (bias+cls contributions); slice 2+n (half=1) has ctr/pred.
// ---------------------------------------------------------------------------
__global__ __launch_bounds__(256) void head_epi(
    const unsigned short* __restrict__ Yh, float* __restrict__ out,
    const float* __restrict__ scales, LvlP P)
{
  const int n = blockIdx.y;
  const int e = blockIdx.x * 256 + threadIdx.x;
  if (e >= TOTROW * 84) return;
  const int pos = e / 84;
  const int j = e - pos * 84;
  const int l = (pos >= P.roff[1]) + (pos >= P.roff[2]) + (pos >= P.roff[3]) + (pos >= P.roff[4]);
  const unsigned short* yc_ = Yh + ((size_t)n * TOTROW + pos) * 128;
  const unsigned short* yb_ = Yh + ((size_t)(2 + n) * TOTROW + pos) * 128;
  float v;
  if (j < 80) {
    const float lg = bf2f(yc_[j]);
    const float ct = bf2f(yb_[80]);
    v = (1.f / (1.f + __expf(-lg))) * (1.f / (1.f + __expf(-ct)));
  } else {
    const int d = j - 80;
    const float stride = sel5f(P.strd, l);
    const int W = sel5i(P.W, l);
    const int local = pos - sel5i(P.roff, l);
    const int gy = local / W, gx = local - gy * W;
    const float pv = bf2f(yb_[81 + d]);
    const float rg = fmaxf(pv * scales[l], 0.f) * stride;
    const float sx = gx * stride, sy = gy * stride;
    v = (d == 0) ? sx - rg : (d == 1) ? sy - rg : (d == 2) ? sx + rg : sy + rg;
  }
  out[((size_t)n * TOTROW + pos) * 84 + j] = v;
}

// ---------------------------------------------------------------------------
extern "C" void kernel_launch(void* const* d_in, const int* in_sizes, int n_in,
                              void* d_out, int out_size, void* d_ws, size_t ws_size,
                              hipStream_t stream)
{
  (void)in_sizes; (void)n_in; (void)out_size; (void)ws_size;

  FPtrs F;
  for (int l = 0; l < 5; ++l) F.f[l] = (const float*)d_in[l];
  const float* cls_w  = (const float*)d_in[5];
  const float* cls_b  = (const float*)d_in[6];
  const float* cls_gw = (const float*)d_in[7];
  const float* cls_gb = (const float*)d_in[8];
  const float* box_w  = (const float*)d_in[9];
  const float* box_b  = (const float*)d_in[10];
  const float* box_gw = (const float*)d_in[11];
  const float* box_gb = (const float*)d_in[12];
  const float* score_w = (const float*)d_in[13];
  const float* score_b = (const float*)d_in[14];
  const float* pred_w  = (const float*)d_in[15];
  const float* pred_b  = (const float*)d_in[16];
  const float* ctr_w   = (const float*)d_in[17];
  const float* ctr_b   = (const float*)d_in[18];
  const float* scales  = (const float*)d_in[19];
  float* out = (float*)d_out;

  static const int Hs[5] = {100, 50, 25, 13, 7};
  static const int Ws[5] = {160, 80, 40, 20, 10};
  LvlP P;
  {
    static const int to[6] = {0, 45, 60, 66, 68, 69};   // 32x12 tiles
    static const int tX[5] = {5, 3, 2, 1, 1};
    static const int po[5] = {0, 16524, 20788, 21922, 22252};
    static const int pe[5] = {16524, 20788, 21922, 22252, 22360};
    static const int ro[6] = {0, 16000, 20000, 21000, 21260, 21330};
    for (int i = 0; i < 6; ++i) { P.tileoff[i] = to[i]; P.roff[i] = ro[i]; }
    for (int i = 0; i < 5; ++i) {
      P.tilesX[i] = tX[i]; P.H[i] = Hs[i]; P.W[i] = Ws[i];
      P.poff[i] = po[i]; P.pend[i] = pe[i];
      P.inv8HW[i] = 1.f / (8.f * Hs[i] * Ws[i]);
      P.strd[i] = (float)(8 << i);
    }
  }

  char* p = (char*)d_ws;
  auto alloc = [&](size_t bytes) {
    char* r = p;
    p += (bytes + 255) & ~(size_t)255;
    return r;
  };
  const size_t XPAD = (size_t)2 * PTOT * 256 * 2;
  const size_t YSZ  = (size_t)2 * TOTROW * 256 * 2;
  unsigned short* Xf  = (unsigned short*)alloc(XPAD);
  unsigned short* Xc  = (unsigned short*)alloc(XPAD);
  unsigned short* Xr  = (unsigned short*)alloc(XPAD);
  unsigned short* Yc  = (unsigned short*)alloc(YSZ);
  unsigned short* Yr  = (unsigned short*)alloc(YSZ);
  unsigned short* Yh  = (unsigned short*)alloc((size_t)4 * TOTROW * 128 * 2);
  unsigned short* wtC = (unsigned short*)alloc(4718592);
  unsigned short* wtR = (unsigned short*)alloc(4718592);
  unsigned short* wth = (unsigned short*)alloc(1179648);
  float* bh    = (float*)alloc(512);
  float* stats = (float*)alloc(4 * 5 * 4 * 32 * 2 * sizeof(float));

  hipMemsetAsync(Xf, 0, XPAD, stream);
  hipMemsetAsync(Xc, 0, XPAD, stream);
  hipMemsetAsync(Xr, 0, XPAD, stream);
  hipMemsetAsync(stats, 0, 4 * 5 * 4 * 32 * 2 * sizeof(float), stream);

  prep_w<<<11520, 256, 0, stream>>>(cls_w, box_w, wtC, wtR,
                                    score_w, score_b, ctr_w, ctr_b,
                                    pred_w, pred_b, wth, bh);
  to_chlast_all<<<dim3(336, 8), 256, 0, stream>>>(F, Xf, P);

  for (int i = 0; i < 4; ++i) {
    const unsigned short* ic_ = (i == 0) ? Xf : Xc;
    const unsigned short* ir_ = (i == 0) ? Xf : Xr;
    float* st = stats + (size_t)i * 5 * 4 * 32 * 2;
    conv_mfma<<<dim3(1104), 256, 0, stream>>>(
        ic_, ir_, Yc, Yr,
        wtC + (size_t)i * 589824, wtR + (size_t)i * 589824,
        cls_b + i * 256, box_b + i * 256, st, P, 1, 256);
    gn_apply<<<dim3((TOTROW * 32 + 255) / 256, 4), 256, 0, stream>>>(
        Yc, Yr, Xc, Xr, st,
        cls_gw + i * 256, cls_gb + i * 256,
        box_gw + i * 256, box_gb + i * 256, P);
  }

  conv_mfma<<<dim3(552), 256, 0, stream>>>(
      Xc, Xr, Yh, nullptr, wth, nullptr, bh, nullptr, nullptr, P, 2, 128);
  head_epi<<<dim3((TOTROW * 84 + 255) / 256, 2), 256, 0, stream>>>(
      Yh, out, scales, P);
}

// Round 12
// 745.530 us; speedup vs baseline: 1.2461x; 1.0485x over previous
//
#include <hip/hip_runtime.h>
#include <cstddef>

#define NLEV 5
#define TOTROW 21330
#define PTOT 22360   // sum of (H+2)*(W+2)

typedef __bf16 bf16x8 __attribute__((ext_vector_type(8)));
typedef float f32x4 __attribute__((ext_vector_type(4)));
typedef unsigned short ushortx8 __attribute__((ext_vector_type(8)));

struct LvlP {
  int tileoff[6];
  int tilesX[5];
  int H[5], W[5];
  int poff[5], pend[5];
  int roff[6];
  float inv8HW[5];
  float strd[5];
};

struct FPtrs { const float* f[5]; };

static __device__ __forceinline__ unsigned short f2bf(float f) {
  union { float f; unsigned u; } v; v.f = f;
  unsigned r = v.u + 0x7fffu + ((v.u >> 16) & 1u);
  return (unsigned short)(r >> 16);
}
static __device__ __forceinline__ float bf2f(unsigned short h) {
  union { unsigned u; float f; } v; v.u = ((unsigned)h) << 16;
  return v.f;
}
static __device__ __forceinline__ int sel5i(const int* a, int l) {
  int v = a[0];
  v = (l == 1) ? a[1] : v; v = (l == 2) ? a[2] : v;
  v = (l == 3) ? a[3] : v; v = (l == 4) ? a[4] : v;
  return v;
}
static __device__ __forceinline__ float sel5f(const float* a, int l) {
  float v = a[0];
  v = (l == 1) ? a[1] : v; v = (l == 2) ? a[2] : v;
  v = (l == 3) ? a[3] : v; v = (l == 4) ? a[4] : v;
  return v;
}

static __device__ __forceinline__ void gload16(const unsigned short* g, unsigned short* l) {
  __builtin_amdgcn_global_load_lds(
      (const __attribute__((address_space(1))) unsigned int*)(const void*)g,
      (__attribute__((address_space(3))) unsigned int*)(void*)l, 16, 0, 0);
}

// ---------------------------------------------------------------------------
// SETUP mega-kernel: one dispatch replaces prep_tower_w + prep_head_w +
// to_chlast (5 levels) + 3 padded-X border-ring zeroes + stats zero.
// Block ranges:
//   [    0,  9216) tower weights fp32 [4][256][256][3][3] ->
//                  bf16 [layer][ch8][tap9][q4][oc256][8]
//   [ 9216, 11520) head weights -> bf16 [ch16][tap9][q4][oc128][8] (+bh)
//   [11520, 14208) NCHW fp32 -> padded channel-last bf16 (336 x 8 flattened)
//   [14208, 14981) border-ring zero for Xf/Xc/Xr (interior is always
//                  overwritten before read -> only the 1030-pos ring/img
//                  needs zeroing: 3.2 MB instead of 68.7 MB of memset)
//   [14981, 15001) stats zero (5120 floats)
// ---------------------------------------------------------------------------
__global__ __launch_bounds__(256) void setup_all(
    const float* __restrict__ cls_w, const float* __restrict__ box_w,
    unsigned short* __restrict__ wtC, unsigned short* __restrict__ wtR,
    const float* __restrict__ sw, const float* __restrict__ sb,
    const float* __restrict__ cw, const float* __restrict__ cbias,
    const float* __restrict__ pw, const float* __restrict__ pb,
    unsigned short* __restrict__ wth, float* __restrict__ bh,
    FPtrs F, unsigned short* __restrict__ Xf,
    unsigned short* __restrict__ Xc, unsigned short* __restrict__ Xr,
    float* __restrict__ stats, LvlP P)
{
  const int bx = blockIdx.x;
  const int tid = threadIdx.x;

  if (bx < 9216) {
    // ---- tower weights ----
    const long e = (long)bx * 256 + tid;
    if (e >= 2359296L) return;
    const int j = (int)(e & 7);
    long r = e >> 3;
    const int oc = (int)(r & 255); r >>= 8;
    const int q = (int)(r & 3); r >>= 2;
    const int tap = (int)(r % 9);
    const long s = r / 9;
    const int ch = (int)(s & 7);
    const int layer = (int)(s >> 3);
    const int ic = ch * 32 + q * 8 + j;
    const long src = (((long)layer * 256 + oc) * 256 + ic) * 9 + tap;
    wtC[e] = f2bf(cls_w[src]);
    wtR[e] = f2bf(box_w[src]);
  } else if (bx < 11520) {
    // ---- head weights ----
    const long e = (long)(bx - 9216) * 256 + tid;
    if (e < 589824L) {
      const int j = (int)(e & 7);
      long r = e >> 3;
      const int oc = (int)(r & 127); r >>= 7;
      const int q = (int)(r & 3); r >>= 2;
      const int tap = (int)(r % 9);
      const int ch = (int)(r / 9);
      const int k = ch * 32 + q * 8 + j;
      float v = 0.f;
      if (oc < 80) { if (k < 256) v = sw[((long)(oc * 256 + k)) * 9 + tap]; }
      else if (oc == 80) { if (k >= 256) v = cw[(long)(k - 256) * 9 + tap]; }
      else if (oc < 85) { if (k >= 256) v = pw[((long)((oc - 81) * 256 + (k - 256))) * 9 + tap]; }
      wth[e] = f2bf(v);
    }
    if (bx == 9216 && tid < 128)
      bh[tid] = (tid < 80) ? sb[tid] : (tid == 80) ? cbias[0] : (tid < 85) ? pb[tid - 81] : 0.f;
  } else if (bx < 14208) {
    // ---- NCHW fp32 -> padded channel-last bf16, all levels ----
    const int b2 = bx - 11520;
    const int iy = b2 / 336;            // 0..7 : n*4 + cb
    const int bx336 = b2 - iy * 336;
    const int l = (bx336 >= 250) + (bx336 >= 313) + (bx336 >= 329) + (bx336 >= 334);
    const int boff[5] = {0, 250, 313, 329, 334};
    const int b0 = sel5i(boff, l);
    const int H = sel5i(P.H, l), W = sel5i(P.W, l);
    const int HW = H * W;
    const int poff = sel5i(P.poff, l);
    const float* feat = F.f[l];

    const int n = iy >> 2, cb = iy & 3;
    const int p0 = (bx336 - b0) * 64;
    __shared__ unsigned short s[64][72];
    const int pl = tid & 63, ci = tid >> 6;
    const float* src = feat + ((size_t)(n * 256 + cb * 64)) * HW;
#pragma unroll
    for (int i = 0; i < 16; ++i) {
      const int c = ci + i * 4;
      const int p = p0 + pl;
      float v = (p < HW) ? src[(size_t)c * HW + p] : 0.f;
      s[c][pl] = f2bf(v);
    }
    __syncthreads();
    const int cl = tid & 63, pi = tid >> 6;
#pragma unroll
    for (int i = 0; i < 16; ++i) {
      const int p = p0 + pi + i * 4;
      if (p < HW) {
        const int y = p / W, x = p - y * W;
        const size_t dst = ((size_t)n * PTOT + poff + (y + 1) * (W + 2) + (x + 1)) * 256
                         + cb * 64 + cl;
        X_write: ;
        unsigned short* Xb = Xf;
        Xb[dst] = s[cl][pi + i * 4];
      }
    }
  } else if (bx < 14981) {
    // ---- border-ring zero: 6180 positions (1030/img x 2 img x 3 bufs),
    //      8 positions per block (32 threads x 8 shorts each) ----
    const int item = (bx - 14208) * 8 + (tid >> 5);
    if (item >= 6180) return;
    const int buf = item / 2060;
    const int r1 = item - buf * 2060;
    const int img = r1 / 1030;
    const int bidx = r1 - img * 1030;
    static const int cum[5] = {0, 524, 788, 922, 992};
    const int l = (bidx >= 524) + (bidx >= 788) + (bidx >= 922) + (bidx >= 992);
    const int b = bidx - sel5i(cum, l);
    const int H = sel5i(P.H, l), W = sel5i(P.W, l);
    const int W2 = W + 2;
    const int poff = sel5i(P.poff, l);
    int pos;
    if (b < W2) pos = poff + b;                                   // top row
    else if (b < 2 * W2) pos = poff + (H + 1) * W2 + (b - W2);    // bottom row
    else {
      const int c = b - 2 * W2;
      const int y = 1 + (c >> 1);
      const int x = (c & 1) ? (W + 1) : 0;
      pos = poff + y * W2 + x;
    }
    unsigned short* Xb = (buf == 0) ? Xf : (buf == 1) ? Xc : Xr;
    ushortx8 z8;
#pragma unroll
    for (int jj = 0; jj < 8; ++jj) z8[jj] = 0;
    *(ushortx8*)(Xb + ((size_t)img * PTOT + pos) * 256 + (tid & 31) * 8) = z8;
  } else {
    // ---- stats zero ----
    const int e = (bx - 14981) * 256 + tid;
    if (e < 5120) stats[e] = 0.f;
  }
}

// ---------------------------------------------------------------------------
// MFMA implicit-GEMM 3x3 conv, all levels in one dispatch. R9/R11 structure
// (proven best): A+B staged to LDS via global_load_lds, single-buffered,
// 2 barriers per 32-ic chunk, LDS 68 KB, af[2][5] A-dedup, XCD-cohort
// swizzle (FETCH 144->39 MB). Occupancy is structurally 2 blocks/CU:
// unified regfile = arch VGPR (~112) + acc AGPR (96) ~= 208 -> 2 waves/EU
// regardless of LDS (R8); B-direct-from-global (R8), launch_bounds>2
// (R4/R7), dbuf pipelines (R1/R2), and GN-fusion into staging (R10:
// reg-staging VALU cost) all regress.
// kimg=1: towers, z=tower*2+n, ny=4, K=256 (8 chunks).
// kimg=2: head SPLIT-K, z=half*2+n, ny=2: half=0 -> score logits from
// cls-X (weight rows 0-7); half=1 -> ctr/pred from box-X (rows 8-15).
// Each writes its own Yh slice; contributions disjoint; both carry bias.
// ---------------------------------------------------------------------------
__global__ __launch_bounds__(256, 2) void conv_mfma(
    const unsigned short* __restrict__ inC, const unsigned short* __restrict__ inR,
    unsigned short* __restrict__ outC, unsigned short* __restrict__ outR,
    const unsigned short* __restrict__ wtC, const unsigned short* __restrict__ wtR,
    const float* __restrict__ bsC, const float* __restrict__ bsR,
    float* __restrict__ stats, LvlP P, int kimg, int octot)
{
  // ---- XCD-cohort remap: ny oc0-blocks of one (tile,z) land on one XCD;
  //      z is constant per XCD -> one image + one weight set per XCD L2.
  const int ny = (kimg == 1) ? 4 : 2;   // oc0 blocks per (tile,z)
  const int nz = 4;
  const int span = ny * 8;
  const int total = 69 * ny * nz;
  const int SG = total / span;
  const int braw = blockIdx.x;
  int j, yy;
  if (braw < SG * span) {
    j = (braw / span) * 8 + (braw & 7);
    yy = (braw % span) >> 3;
  } else {
    const int p = braw - SG * span;
    const int cpx = (total - SG * span) / ny;
    j = SG * 8 + p % cpx;
    yy = p / cpx;
  }
  const int z = j % nz;
  const int bt = j / nz;                // tile index 0..68
  const int oc0 = yy << 6;

  const int l = (bt >= P.tileoff[1]) + (bt >= P.tileoff[2])
              + (bt >= P.tileoff[3]) + (bt >= P.tileoff[4]);
  const int t = bt - sel5i(P.tileoff, l);
  const int tX = sel5i(P.tilesX, l);
  const int ty = t / tX, tx = t - ty * tX;
  const int x0 = tx << 5, y0 = ty * 12;
  const int H = sel5i(P.H, l), W = sel5i(P.W, l);
  const int W2 = W + 2;
  const int pbase = sel5i(P.poff, l);
  const int pmax = sel5i(P.pend, l) - 1;
  const int rbase = sel5i(P.roff, l);

  const unsigned short *A, *wt;
  const float* bs; unsigned short* out;
  int wchoff = 0;
  if (kimg == 1) {
    const int tower = z >> 1, n = z & 1;
    A = (tower ? inR : inC) + (size_t)n * PTOT * 256;
    wt = tower ? wtR : wtC;
    bs = tower ? bsR : bsC;
    out = (tower ? outR : outC) + (size_t)n * TOTROW * octot;
  } else {
    const int half = z >> 1, n = z & 1;
    A = (half ? inR : inC) + (size_t)n * PTOT * 256;
    wt = wtC; bs = bsC;
    wchoff = half * 8;                  // weight rows 8-15 for the box half
    out = outC + (size_t)z * TOTROW * octot;   // Yh slice [half*2+n]
  }

  __shared__ unsigned short sA[512 * 32];   // [pos 476(+pad)][part4][8ic]  32 KB
  __shared__ unsigned short sB[36 * 512];   // [tap][q][oc64][8ic]          36 KB

  const int tid = threadIdx.x;
  const int wv = tid >> 6, lane = tid & 63;
  const int t15 = lane & 15, q = lane >> 4;

  // per-lane A-staging source offsets (in shorts): 8 instrs/wave, 32 total
  unsigned aoff[8];
#pragma unroll
  for (int it = 0; it < 8; ++it) {
    const int inst = wv + it * 4;
    const int item = (inst << 6) + lane;
    int pos = item >> 2; pos = (pos > 475) ? 475 : pos;
    const int part = item & 3;
    const int hy = pos / 34, hx = pos - hy * 34;
    int pidx = pbase + (y0 + hy) * W2 + (x0 + hx);
    pidx = (pidx > pmax) ? pmax : pidx;
    aoff[it] = ((unsigned)pidx << 8) + (part << 3);
  }

  f32x4 acc[6][4];
#pragma unroll
  for (int g = 0; g < 4; ++g) {
    const float b = bs[oc0 + g * 16 + t15];
#pragma unroll
    for (int f = 0; f < 6; ++f) {
      acc[f][g][0] = b; acc[f][g][1] = b; acc[f][g][2] = b; acc[f][g][3] = b;
    }
  }

  for (int ch = 0; ch < 8; ++ch) {
    const unsigned icb = (unsigned)ch << 5;
    __syncthreads();
    // A stage: 32 wave-instructions of 64 lanes x 16 B
#pragma unroll
    for (int it = 0; it < 8; ++it)
      gload16(A + aoff[it] + icb, sA + ((wv + it * 4) << 9));
    // B stage: 36 wave-instructions, fully contiguous 1 KB each
    const unsigned short* wb = wt + ((size_t)((ch + wchoff) * 36) * octot + oc0) * 8 + (lane << 3);
#pragma unroll
    for (int it = 0; it < 9; ++it)
      gload16(wb + (size_t)(wv + it * 4) * octot * 8, sB + ((wv + it * 4) << 9));
    __syncthreads();

#pragma unroll
    for (int kx = 0; kx < 3; ++kx) {
      // hoist the 5 distinct A rows (x 2 col-halves) for this kx
      bf16x8 af[2][5];
#pragma unroll
      for (int fc = 0; fc < 2; ++fc)
#pragma unroll
        for (int r = 0; r < 5; ++r) {
          const int pos = (wv * 3 + r) * 34 + fc * 16 + t15 + kx;
          af[fc][r] = *(const bf16x8*)(sA + ((pos * 4 + q) << 3));
        }
#pragma unroll
      for (int ky = 0; ky < 3; ++ky) {
        const int tap = ky * 3 + kx;
        bf16x8 b[4];
#pragma unroll
        for (int g = 0; g < 4; ++g)
          b[g] = *(const bf16x8*)(sB + ((((tap * 4 + q) << 6) + g * 16 + t15) << 3));
#pragma unroll
        for (int fr = 0; fr < 3; ++fr)
#pragma unroll
          for (int fc = 0; fc < 2; ++fc) {
            const bf16x8 a = af[fc][fr + ky];
#pragma unroll
            for (int g = 0; g < 4; ++g)
              acc[fr * 2 + fc][g] =
                  __builtin_amdgcn_mfma_f32_16x16x32_bf16(a, b[g], acc[fr * 2 + fc][g], 0, 0, 0);
          }
      }
    }
  }

  // epilogue: store bf16 + fused GN partial stats
#pragma unroll
  for (int g = 0; g < 4; ++g) {
    const int oc = oc0 + g * 16 + t15;
    float s = 0.f, ss = 0.f;
#pragma unroll
    for (int f = 0; f < 6; ++f) {
      const int fr = f >> 1, fc = f & 1;
      const int gy = y0 + wv * 3 + fr;
#pragma unroll
      for (int rg = 0; rg < 4; ++rg) {
        const int gx = x0 + fc * 16 + q * 4 + rg;
        if (gy < H && gx < W) {
          const float v = acc[f][g][rg];
          out[(size_t)(rbase + gy * W + gx) * octot + oc] = f2bf(v);
          s += v; ss += v * v;
        }
      }
    }
    if (stats) {
      s += __shfl_xor(s, 1);  ss += __shfl_xor(ss, 1);
      s += __shfl_xor(s, 2);  ss += __shfl_xor(ss, 2);
      s += __shfl_xor(s, 4);  ss += __shfl_xor(ss, 4);
      s += __shfl_xor(s, 16); ss += __shfl_xor(ss, 16);
      if ((lane & 55) == 0) {   // lanes 0 and 8 hold the two GN groups of this g
        float* st = stats + (((size_t)l * 4 + z) * 32 + (oc >> 3)) * 2;
        atomicAdd(st, s); atomicAdd(st + 1, ss);
      }
    }
  }
}

// ---------------------------------------------------------------------------
// GN apply + ReLU, merged levels: reads unpadded Y, writes padded X interior.
// grid: (ceil(21330*32/256), 4 imgs)
// ---------------------------------------------------------------------------
__global__ __launch_bounds__(256) void gn_apply(
    const unsigned short* __restrict__ Yc, const unsigned short* __restrict__ Yr,
    unsigned short* __restrict__ Xc, unsigned short* __restrict__ Xr,
    const float* __restrict__ stats,
    const float* __restrict__ gwC, const float* __restrict__ gbC,
    const float* __restrict__ gwR, const float* __restrict__ gbR, LvlP P)
{
  const int img = blockIdx.y;
  const int tower = img >> 1, n = img & 1;
  const int e = blockIdx.x * 256 + threadIdx.x;
  const int pos = e >> 5;
  const int g = e & 31;
  if (pos >= TOTROW) return;
  const int l = (pos >= P.roff[1]) + (pos >= P.roff[2]) + (pos >= P.roff[3]) + (pos >= P.roff[4]);
  const int W = sel5i(P.W, l);
  const int local = pos - sel5i(P.roff, l);
  const int y = local / W, x = local - y * W;
  const size_t dst = ((size_t)n * PTOT + sel5i(P.poff, l) + (y + 1) * (W + 2) + (x + 1)) * 256 + g * 8;
  const size_t srco = ((size_t)n * TOTROW + pos) * 256 + g * 8;
  const unsigned short* Y = (tower ? Yr : Yc) + srco;
  unsigned short* X = (tower ? Xr : Xc) + dst;
  const float* gw = (tower ? gwR : gwC) + g * 8;
  const float* gb = (tower ? gbR : gbC) + g * 8;
  const float* st = stats + (((size_t)l * 4 + img) * 32 + g) * 2;
  const float inv = sel5f(P.inv8HW, l);
  const float m = st[0] * inv;
  const float var = st[1] * inv - m * m;
  const float rs = rsqrtf(var + 1e-5f);
  ushortx8 yv = *(const ushortx8*)Y;
  ushortx8 xv;
#pragma unroll
  for (int j = 0; j < 8; ++j) {
    const float yj = bf2f(yv[j]);
    const float v = (yj - m) * rs * gw[j] + gb[j];
    xv[j] = f2bf(fmaxf(v, 0.f));
  }
  *(ushortx8*)X = xv;
}

// ---------------------------------------------------------------------------
// Head epilogue, merged levels. Split-K Yh: slice n (half=0) has score
// logits (bias+cls contributions); slice 2+n (half=1) has ctr/pred.
// ---------------------------------------------------------------------------
__global__ __launch_bounds__(256) void head_epi(
    const unsigned short* __restrict__ Yh, float* __restrict__ out,
    const float* __restrict__ scales, LvlP P)
{
  const int n = blockIdx.y;
  const int e = blockIdx.x * 256 + threadIdx.x;
  if (e >= TOTROW * 84) return;
  const int pos = e / 84;
  const int j = e - pos * 84;
  const int l = (pos >= P.roff[1]) + (pos >= P.roff[2]) + (pos >= P.roff[3]) + (pos >= P.roff[4]);
  const unsigned short* yc_ = Yh + ((size_t)n * TOTROW + pos) * 128;
  const unsigned short* yb_ = Yh + ((size_t)(2 + n) * TOTROW + pos) * 128;
  float v;
  if (j < 80) {
    const float lg = bf2f(yc_[j]);
    const float ct = bf2f(yb_[80]);
    v = (1.f / (1.f + __expf(-lg))) * (1.f / (1.f + __expf(-ct)));
  } else {
    const int d = j - 80;
    const float stride = sel5f(P.strd, l);
    const int W = sel5i(P.W, l);
    const int local = pos - sel5i(P.roff, l);
    const int gy = local / W, gx = local - gy * W;
    const float pv = bf2f(yb_[81 + d]);
    const float rg = fmaxf(pv * scales[l], 0.f) * stride;
    const float sx = gx * stride, sy = gy * stride;
    v = (d == 0) ? sx - rg : (d == 1) ? sy - rg : (d == 2) ? sx + rg : sy + rg;
  }
  out[((size_t)n * TOTROW + pos) * 84 + j] = v;
}

// ---------------------------------------------------------------------------
extern "C" void kernel_launch(void* const* d_in, const int* in_sizes, int n_in,
                              void* d_out, int out_size, void* d_ws, size_t ws_size,
                              hipStream_t stream)
{
  (void)in_sizes; (void)n_in; (void)out_size; (void)ws_size;

  FPtrs F;
  for (int l = 0; l < 5; ++l) F.f[l] = (const float*)d_in[l];
  const float* cls_w  = (const float*)d_in[5];
  const float* cls_b  = (const float*)d_in[6];
  const float* cls_gw = (const float*)d_in[7];
  const float* cls_gb = (const float*)d_in[8];
  const float* box_w  = (const float*)d_in[9];
  const float* box_b  = (const float*)d_in[10];
  const float* box_gw = (const float*)d_in[11];
  const float* box_gb = (const float*)d_in[12];
  const float* score_w = (const float*)d_in[13];
  const float* score_b = (const float*)d_in[14];
  const float* pred_w  = (const float*)d_in[15];
  const float* pred_b  = (const float*)d_in[16];
  const float* ctr_w   = (const float*)d_in[17];
  const float* ctr_b   = (const float*)d_in[18];
  const float* scales  = (const float*)d_in[19];
  float* out = (float*)d_out;

  static const int Hs[5] = {100, 50, 25, 13, 7};
  static const int Ws[5] = {160, 80, 40, 20, 10};
  LvlP P;
  {
    static const int to[6] = {0, 45, 60, 66, 68, 69};   // 32x12 tiles
    static const int tX[5] = {5, 3, 2, 1, 1};
    static const int po[5] = {0, 16524, 20788, 21922, 22252};
    static const int pe[5] = {16524, 20788, 21922, 22252, 22360};
    static const int ro[6] = {0, 16000, 20000, 21000, 21260, 21330};
    for (int i = 0; i < 6; ++i) { P.tileoff[i] = to[i]; P.roff[i] = ro[i]; }
    for (int i = 0; i < 5; ++i) {
      P.tilesX[i] = tX[i]; P.H[i] = Hs[i]; P.W[i] = Ws[i];
      P.poff[i] = po[i]; P.pend[i] = pe[i];
      P.inv8HW[i] = 1.f / (8.f * Hs[i] * Ws[i]);
      P.strd[i] = (float)(8 << i);
    }
  }

  char* p = (char*)d_ws;
  auto alloc = [&](size_t bytes) {
    char* r = p;
    p += (bytes + 255) & ~(size_t)255;
    return r;
  };
  const size_t XPAD = (size_t)2 * PTOT * 256 * 2;
  const size_t YSZ  = (size_t)2 * TOTROW * 256 * 2;
  unsigned short* Xf  = (unsigned short*)alloc(XPAD);
  unsigned short* Xc  = (unsigned short*)alloc(XPAD);
  unsigned short* Xr  = (unsigned short*)alloc(XPAD);
  unsigned short* Yc  = (unsigned short*)alloc(YSZ);
  unsigned short* Yr  = (unsigned short*)alloc(YSZ);
  unsigned short* Yh  = (unsigned short*)alloc((size_t)4 * TOTROW * 128 * 2);
  unsigned short* wtC = (unsigned short*)alloc(4718592);
  unsigned short* wtR = (unsigned short*)alloc(4718592);
  unsigned short* wth = (unsigned short*)alloc(1179648);
  float* bh    = (float*)alloc(512);
  float* stats = (float*)alloc(4 * 5 * 4 * 32 * 2 * sizeof(float));

  setup_all<<<15001, 256, 0, stream>>>(cls_w, box_w, wtC, wtR,
                                       score_w, score_b, ctr_w, ctr_b,
                                       pred_w, pred_b, wth, bh,
                                       F, Xf, Xc, Xr, stats, P);

  for (int i = 0; i < 4; ++i) {
    const unsigned short* ic_ = (i == 0) ? Xf : Xc;
    const unsigned short* ir_ = (i == 0) ? Xf : Xr;
    float* st = stats + (size_t)i * 5 * 4 * 32 * 2;
    conv_mfma<<<dim3(1104), 256, 0, stream>>>(
        ic_, ir_, Yc, Yr,
        wtC + (size_t)i * 589824, wtR + (size_t)i * 589824,
        cls_b + i * 256, box_b + i * 256, st, P, 1, 256);
    gn_apply<<<dim3((TOTROW * 32 + 255) / 256, 4), 256, 0, stream>>>(
        Yc, Yr, Xc, Xr, st,
        cls_gw + i * 256, cls_gb + i * 256,
        box_gw + i * 256, box_gb + i * 256, P);
  }

  conv_mfma<<<dim3(552), 256, 0, stream>>>(
      Xc, Xr, Yh, nullptr, wth, nullptr, bh, nullptr, nullptr, P, 2, 128);
  head_epi<<<dim3((TOTROW * 84 + 255) / 256, 2), 256, 0, stream>>>(
      Yh, out, scales, P);
}

// Round 13
// 727.487 us; speedup vs baseline: 1.2770x; 1.0248x over previous
//
#include <hip/hip_runtime.h>
#include <cstddef>

#define NLEV 5
#define TOTROW 21330
#define PTOT 22360   // sum of (H+2)*(W+2)

typedef __bf16 bf16x8 __attribute__((ext_vector_type(8)));
typedef float f32x4 __attribute__((ext_vector_type(4)));
typedef unsigned short ushortx8 __attribute__((ext_vector_type(8)));

struct LvlP {
  int tileoff[6];
  int tilesX[5];
  int H[5], W[5];
  int poff[5], pend[5];
  int roff[6];
  float inv8HW[5];
  float strd[5];
};

struct FPtrs { const float* f[5]; };

static __device__ __forceinline__ unsigned short f2bf(float f) {
  union { float f; unsigned u; } v; v.f = f;
  unsigned r = v.u + 0x7fffu + ((v.u >> 16) & 1u);
  return (unsigned short)(r >> 16);
}
static __device__ __forceinline__ float bf2f(unsigned short h) {
  union { unsigned u; float f; } v; v.u = ((unsigned)h) << 16;
  return v.f;
}
static __device__ __forceinline__ int sel5i(const int* a, int l) {
  int v = a[0];
  v = (l == 1) ? a[1] : v; v = (l == 2) ? a[2] : v;
  v = (l == 3) ? a[3] : v; v = (l == 4) ? a[4] : v;
  return v;
}
static __device__ __forceinline__ float sel5f(const float* a, int l) {
  float v = a[0];
  v = (l == 1) ? a[1] : v; v = (l == 2) ? a[2] : v;
  v = (l == 3) ? a[3] : v; v = (l == 4) ? a[4] : v;
  return v;
}

static __device__ __forceinline__ void gload16(const unsigned short* g, unsigned short* l) {
  __builtin_amdgcn_global_load_lds(
      (const __attribute__((address_space(1))) unsigned int*)(const void*)g,
      (__attribute__((address_space(3))) unsigned int*)(void*)l, 16, 0, 0);
}

// ---------------------------------------------------------------------------
// SETUP mega-kernel: one dispatch (15001 blocks). Ranges:
//   [    0,  9216) tower weights -> bf16 [layer][ch8][tap9][q4][oc256][8]
//   [ 9216, 11520) head weights -> bf16 [ch16][tap9][q4][oc128][8] (+bh)
//   [11520, 14208) NCHW fp32 -> padded channel-last bf16 (336 x 8 flattened)
//   [14208, 14981) border-ring zero for Xf/Xc/Xr
//   [14981, 15001) stats zero
// ---------------------------------------------------------------------------
__global__ __launch_bounds__(256) void setup_all(
    const float* __restrict__ cls_w, const float* __restrict__ box_w,
    unsigned short* __restrict__ wtC, unsigned short* __restrict__ wtR,
    const float* __restrict__ sw, const float* __restrict__ sb,
    const float* __restrict__ cw, const float* __restrict__ cbias,
    const float* __restrict__ pw, const float* __restrict__ pb,
    unsigned short* __restrict__ wth, float* __restrict__ bh,
    FPtrs F, unsigned short* __restrict__ Xf,
    unsigned short* __restrict__ Xc, unsigned short* __restrict__ Xr,
    float* __restrict__ stats, LvlP P)
{
  const int bx = blockIdx.x;
  const int tid = threadIdx.x;

  if (bx < 9216) {
    const long e = (long)bx * 256 + tid;
    if (e >= 2359296L) return;
    const int j = (int)(e & 7);
    long r = e >> 3;
    const int oc = (int)(r & 255); r >>= 8;
    const int q = (int)(r & 3); r >>= 2;
    const int tap = (int)(r % 9);
    const long s = r / 9;
    const int ch = (int)(s & 7);
    const int layer = (int)(s >> 3);
    const int ic = ch * 32 + q * 8 + j;
    const long src = (((long)layer * 256 + oc) * 256 + ic) * 9 + tap;
    wtC[e] = f2bf(cls_w[src]);
    wtR[e] = f2bf(box_w[src]);
  } else if (bx < 11520) {
    const long e = (long)(bx - 9216) * 256 + tid;
    if (e < 589824L) {
      const int j = (int)(e & 7);
      long r = e >> 3;
      const int oc = (int)(r & 127); r >>= 7;
      const int q = (int)(r & 3); r >>= 2;
      const int tap = (int)(r % 9);
      const int ch = (int)(r / 9);
      const int k = ch * 32 + q * 8 + j;
      float v = 0.f;
      if (oc < 80) { if (k < 256) v = sw[((long)(oc * 256 + k)) * 9 + tap]; }
      else if (oc == 80) { if (k >= 256) v = cw[(long)(k - 256) * 9 + tap]; }
      else if (oc < 85) { if (k >= 256) v = pw[((long)((oc - 81) * 256 + (k - 256))) * 9 + tap]; }
      wth[e] = f2bf(v);
    }
    if (bx == 9216 && tid < 128)
      bh[tid] = (tid < 80) ? sb[tid] : (tid == 80) ? cbias[0] : (tid < 85) ? pb[tid - 81] : 0.f;
  } else if (bx < 14208) {
    const int b2 = bx - 11520;
    const int iy = b2 / 336;            // 0..7 : n*4 + cb
    const int bx336 = b2 - iy * 336;
    const int l = (bx336 >= 250) + (bx336 >= 313) + (bx336 >= 329) + (bx336 >= 334);
    const int boff[5] = {0, 250, 313, 329, 334};
    const int b0 = sel5i(boff, l);
    const int H = sel5i(P.H, l), W = sel5i(P.W, l);
    const int HW = H * W;
    const int poff = sel5i(P.poff, l);
    const float* feat = F.f[l];

    const int n = iy >> 2, cb = iy & 3;
    const int p0 = (bx336 - b0) * 64;
    __shared__ unsigned short s[64][72];
    const int pl = tid & 63, ci = tid >> 6;
    const float* src = feat + ((size_t)(n * 256 + cb * 64)) * HW;
#pragma unroll
    for (int i = 0; i < 16; ++i) {
      const int c = ci + i * 4;
      const int p = p0 + pl;
      float v = (p < HW) ? src[(size_t)c * HW + p] : 0.f;
      s[c][pl] = f2bf(v);
    }
    __syncthreads();
    const int cl = tid & 63, pi = tid >> 6;
#pragma unroll
    for (int i = 0; i < 16; ++i) {
      const int p = p0 + pi + i * 4;
      if (p < HW) {
        const int y = p / W, x = p - y * W;
        const size_t dst = ((size_t)n * PTOT + poff + (y + 1) * (W + 2) + (x + 1)) * 256
                         + cb * 64 + cl;
        Xf[dst] = s[cl][pi + i * 4];
      }
    }
  } else if (bx < 14981) {
    const int item = (bx - 14208) * 8 + (tid >> 5);
    if (item >= 6180) return;
    const int buf = item / 2060;
    const int r1 = item - buf * 2060;
    const int img = r1 / 1030;
    const int bidx = r1 - img * 1030;
    static const int cum[5] = {0, 524, 788, 922, 992};
    const int l = (bidx >= 524) + (bidx >= 788) + (bidx >= 922) + (bidx >= 992);
    const int b = bidx - sel5i(cum, l);
    const int H = sel5i(P.H, l), W = sel5i(P.W, l);
    const int W2 = W + 2;
    const int poff = sel5i(P.poff, l);
    int pos;
    if (b < W2) pos = poff + b;
    else if (b < 2 * W2) pos = poff + (H + 1) * W2 + (b - W2);
    else {
      const int c = b - 2 * W2;
      const int y = 1 + (c >> 1);
      const int x = (c & 1) ? (W + 1) : 0;
      pos = poff + y * W2 + x;
    }
    unsigned short* Xb = (buf == 0) ? Xf : (buf == 1) ? Xc : Xr;
    ushortx8 z8;
#pragma unroll
    for (int jj = 0; jj < 8; ++jj) z8[jj] = 0;
    *(ushortx8*)(Xb + ((size_t)img * PTOT + pos) * 256 + (tid & 31) * 8) = z8;
  } else {
    const int e = (bx - 14981) * 256 + tid;
    if (e < 5120) stats[e] = 0.f;
  }
}

// ---------------------------------------------------------------------------
// MFMA implicit-GEMM 3x3 conv, all levels in one dispatch.
// R13: oc32 retile of the R9/R11 structure. Block tile M=384 x N=32:
// acc[6][2] = 48 AGPR -> unified regs ~155 <= 170 -> 3 waves/EU naturally
// (NO launch_bounds coercion -- R4/R7 lesson). LDS = A 32 KB + B 18 KB =
// 50 KB -> 3 blocks/CU (150 KB). B stays in LDS (R8). Same 2-barrier
// chunk loop, af[2][5] A-dedup, XCD-cohort swizzle (all oc-blocks of one
// (tile,z) on one XCD; z constant per XCD).
// B stage: 18 x 1KB wave-instructions; per-lane global src row-split
// (lanes 0-31 -> row 2i, 32-63 -> row 2i+1) since the oc32 slice is
// non-contiguous across (tap,q) rows.
// kimg=1: towers, z=tower*2+n, ny=8, grid 2208.
// kimg=2: head SPLIT-K, z=half*2+n, ny=4, grid 1104; half=0 -> score
// logits from cls-X (weight rows 0-7); half=1 -> ctr/pred from box-X
// (rows 8-15). Yh slices disjoint; both carry bias.
// ---------------------------------------------------------------------------
__global__ __launch_bounds__(256, 2) void conv_mfma(
    const unsigned short* __restrict__ inC, const unsigned short* __restrict__ inR,
    unsigned short* __restrict__ outC, unsigned short* __restrict__ outR,
    const unsigned short* __restrict__ wtC, const unsigned short* __restrict__ wtR,
    const float* __restrict__ bsC, const float* __restrict__ bsR,
    float* __restrict__ stats, LvlP P, int kimg, int octot)
{
  // ---- XCD-cohort remap ----
  const int ny = (kimg == 1) ? 8 : 4;   // oc0 blocks (of 32) per (tile,z)
  const int nz = 4;
  const int span = ny * 8;
  const int total = 69 * ny * nz;
  const int SG = total / span;
  const int braw = blockIdx.x;
  int j, yy;
  if (braw < SG * span) {
    j = (braw / span) * 8 + (braw & 7);
    yy = (braw % span) >> 3;
  } else {
    const int p = braw - SG * span;
    const int cpx = (total - SG * span) / ny;
    j = SG * 8 + p % cpx;
    yy = p / cpx;
  }
  const int z = j % nz;
  const int bt = j / nz;                // tile index 0..68
  const int oc0 = yy << 5;

  const int l = (bt >= P.tileoff[1]) + (bt >= P.tileoff[2])
              + (bt >= P.tileoff[3]) + (bt >= P.tileoff[4]);
  const int t = bt - sel5i(P.tileoff, l);
  const int tX = sel5i(P.tilesX, l);
  const int ty = t / tX, tx = t - ty * tX;
  const int x0 = tx << 5, y0 = ty * 12;
  const int H = sel5i(P.H, l), W = sel5i(P.W, l);
  const int W2 = W + 2;
  const int pbase = sel5i(P.poff, l);
  const int pmax = sel5i(P.pend, l) - 1;
  const int rbase = sel5i(P.roff, l);

  const unsigned short *A, *wt;
  const float* bs; unsigned short* out;
  int wchoff = 0;
  if (kimg == 1) {
    const int tower = z >> 1, n = z & 1;
    A = (tower ? inR : inC) + (size_t)n * PTOT * 256;
    wt = tower ? wtR : wtC;
    bs = tower ? bsR : bsC;
    out = (tower ? outR : outC) + (size_t)n * TOTROW * octot;
  } else {
    const int half = z >> 1, n = z & 1;
    A = (half ? inR : inC) + (size_t)n * PTOT * 256;
    wt = wtC; bs = bsC;
    wchoff = half * 8;                  // weight rows 8-15 for the box half
    out = outC + (size_t)z * TOTROW * octot;   // Yh slice [half*2+n]
  }

  __shared__ unsigned short sA[512 * 32];   // [pos 476(+pad)][part4][8ic]  32 KB
  __shared__ unsigned short sB[36 * 256];   // [tap*4+q][oc32][8ic]         18 KB

  const int tid = threadIdx.x;
  const int wv = tid >> 6, lane = tid & 63;
  const int t15 = lane & 15, q = lane >> 4;

  // per-lane A-staging source offsets (in shorts): 8 instrs/wave, 32 total
  unsigned aoff[8];
#pragma unroll
  for (int it = 0; it < 8; ++it) {
    const int inst = wv + it * 4;
    const int item = (inst << 6) + lane;
    int pos = item >> 2; pos = (pos > 475) ? 475 : pos;
    const int part = item & 3;
    const int hy = pos / 34, hx = pos - hy * 34;
    int pidx = pbase + (y0 + hy) * W2 + (x0 + hx);
    pidx = (pidx > pmax) ? pmax : pidx;
    aoff[it] = ((unsigned)pidx << 8) + (part << 3);
  }

  f32x4 acc[6][2];
#pragma unroll
  for (int g = 0; g < 2; ++g) {
    const float b = bs[oc0 + g * 16 + t15];
#pragma unroll
    for (int f = 0; f < 6; ++f) {
      acc[f][g][0] = b; acc[f][g][1] = b; acc[f][g][2] = b; acc[f][g][3] = b;
    }
  }

  // B-stage per-lane base: lanes 0-31 cover one 512B row (32 oc x 16B),
  // lanes 32-63 the next row (row stride in global = octot*8 shorts).
  const int rsub = lane >> 5;
  const unsigned short* wbase = wt + (size_t)oc0 * 8 + (size_t)(lane & 31) * 8;

  for (int ch = 0; ch < 8; ++ch) {
    const unsigned icb = (unsigned)ch << 5;
    __syncthreads();
    // A stage: 32 wave-instructions of 64 lanes x 16 B
#pragma unroll
    for (int it = 0; it < 8; ++it)
      gload16(A + aoff[it] + icb, sA + ((wv + it * 4) << 9));
    // B stage: 18 wave-instructions, each 1 KB = rows {2i, 2i+1}
    const unsigned short* wch = wbase + (size_t)(ch + wchoff) * 36 * octot * 8;
#pragma unroll
    for (int it = 0; it < 5; ++it) {
      const int inst = wv + it * 4;
      if (inst < 18)
        gload16(wch + (size_t)(2 * inst + rsub) * octot * 8, sB + inst * 512);
    }
    __syncthreads();

#pragma unroll
    for (int kx = 0; kx < 3; ++kx) {
      // hoist the 5 distinct A rows (x 2 col-halves) for this kx
      bf16x8 af[2][5];
#pragma unroll
      for (int fc = 0; fc < 2; ++fc)
#pragma unroll
        for (int r = 0; r < 5; ++r) {
          const int pos = (wv * 3 + r) * 34 + fc * 16 + t15 + kx;
          af[fc][r] = *(const bf16x8*)(sA + ((pos * 4 + q) << 3));
        }
#pragma unroll
      for (int ky = 0; ky < 3; ++ky) {
        const int tap = ky * 3 + kx;
        bf16x8 b[2];
#pragma unroll
        for (int g = 0; g < 2; ++g)
          b[g] = *(const bf16x8*)(sB + ((((tap * 4 + q) << 5) + g * 16 + t15) << 3));
#pragma unroll
        for (int fr = 0; fr < 3; ++fr)
#pragma unroll
          for (int fc = 0; fc < 2; ++fc) {
            const bf16x8 a = af[fc][fr + ky];
#pragma unroll
            for (int g = 0; g < 2; ++g)
              acc[fr * 2 + fc][g] =
                  __builtin_amdgcn_mfma_f32_16x16x32_bf16(a, b[g], acc[fr * 2 + fc][g], 0, 0, 0);
          }
      }
    }
  }

  // epilogue: store bf16 + fused GN partial stats
#pragma unroll
  for (int g = 0; g < 2; ++g) {
    const int oc = oc0 + g * 16 + t15;
    float s = 0.f, ss = 0.f;
#pragma unroll
    for (int f = 0; f < 6; ++f) {
      const int fr = f >> 1, fc = f & 1;
      const int gy = y0 + wv * 3 + fr;
#pragma unroll
      for (int rg = 0; rg < 4; ++rg) {
        const int gx = x0 + fc * 16 + q * 4 + rg;
        if (gy < H && gx < W) {
          const float v = acc[f][g][rg];
          out[(size_t)(rbase + gy * W + gx) * octot + oc] = f2bf(v);
          s += v; ss += v * v;
        }
      }
    }
    if (stats) {
      s += __shfl_xor(s, 1);  ss += __shfl_xor(ss, 1);
      s += __shfl_xor(s, 2);  ss += __shfl_xor(ss, 2);
      s += __shfl_xor(s, 4);  ss += __shfl_xor(ss, 4);
      s += __shfl_xor(s, 16); ss += __shfl_xor(ss, 16);
      if ((lane & 55) == 0) {   // lanes 0 and 8 hold the two GN groups of this g
        float* st = stats + (((size_t)l * 4 + z) * 32 + (oc >> 3)) * 2;
        atomicAdd(st, s); atomicAdd(st + 1, ss);
      }
    }
  }
}

// ---------------------------------------------------------------------------
// GN apply + ReLU, merged levels: reads unpadded Y, writes padded X interior.
// grid: (ceil(21330*32/256), 4 imgs)
// ---------------------------------------------------------------------------
__global__ __launch_bounds__(256) void gn_apply(
    const unsigned short* __restrict__ Yc, const unsigned short* __restrict__ Yr,
    unsigned short* __restrict__ Xc, unsigned short* __restrict__ Xr,
    const float* __restrict__ stats,
    const float* __restrict__ gwC, const float* __restrict__ gbC,
    const float* __restrict__ gwR, const float* __restrict__ gbR, LvlP P)
{
  const int img = blockIdx.y;
  const int tower = img >> 1, n = img & 1;
  const int e = blockIdx.x * 256 + threadIdx.x;
  const int pos = e >> 5;
  const int g = e & 31;
  if (pos >= TOTROW) return;
  const int l = (pos >= P.roff[1]) + (pos >= P.roff[2]) + (pos >= P.roff[3]) + (pos >= P.roff[4]);
  const int W = sel5i(P.W, l);
  const int local = pos - sel5i(P.roff, l);
  const int y = local / W, x = local - y * W;
  const size_t dst = ((size_t)n * PTOT + sel5i(P.poff, l) + (y + 1) * (W + 2) + (x + 1)) * 256 + g * 8;
  const size_t srco = ((size_t)n * TOTROW + pos) * 256 + g * 8;
  const unsigned short* Y = (tower ? Yr : Yc) + srco;
  unsigned short* X = (tower ? Xr : Xc) + dst;
  const float* gw = (tower ? gwR : gwC) + g * 8;
  const float* gb = (tower ? gbR : gbC) + g * 8;
  const float* st = stats + (((size_t)l * 4 + img) * 32 + g) * 2;
  const float inv = sel5f(P.inv8HW, l);
  const float m = st[0] * inv;
  const float var = st[1] * inv - m * m;
  const float rs = rsqrtf(var + 1e-5f);
  ushortx8 yv = *(const ushortx8*)Y;
  ushortx8 xv;
#pragma unroll
  for (int j = 0; j < 8; ++j) {
    const float yj = bf2f(yv[j]);
    const float v = (yj - m) * rs * gw[j] + gb[j];
    xv[j] = f2bf(fmaxf(v, 0.f));
  }
  *(ushortx8*)X = xv;
}

// ---------------------------------------------------------------------------
// Head epilogue, merged levels. Split-K Yh: slice n (half=0) has score
// logits (bias+cls contributions); slice 2+n (half=1) has ctr/pred.
// ---------------------------------------------------------------------------
__global__ __launch_bounds__(256) void head_epi(
    const unsigned short* __restrict__ Yh, float* __restrict__ out,
    const float* __restrict__ scales, LvlP P)
{
  const int n = blockIdx.y;
  const int e = blockIdx.x * 256 + threadIdx.x;
  if (e >= TOTROW * 84) return;
  const int pos = e / 84;
  const int j = e - pos * 84;
  const int l = (pos >= P.roff[1]) + (pos >= P.roff[2]) + (pos >= P.roff[3]) + (pos >= P.roff[4]);
  const unsigned short* yc_ = Yh + ((size_t)n * TOTROW + pos) * 128;
  const unsigned short* yb_ = Yh + ((size_t)(2 + n) * TOTROW + pos) * 128;
  float v;
  if (j < 80) {
    const float lg = bf2f(yc_[j]);
    const float ct = bf2f(yb_[80]);
    v = (1.f / (1.f + __expf(-lg))) * (1.f / (1.f + __expf(-ct)));
  } else {
    const int d = j - 80;
    const float stride = sel5f(P.strd, l);
    const int W = sel5i(P.W, l);
    const int local = pos - sel5i(P.roff, l);
    const int gy = local / W, gx = local - gy * W;
    const float pv = bf2f(yb_[81 + d]);
    const float rg = fmaxf(pv * scales[l], 0.f) * stride;
    const float sx = gx * stride, sy = gy * stride;
    v = (d == 0) ? sx - rg : (d == 1) ? sy - rg : (d == 2) ? sx + rg : sy + rg;
  }
  out[((size_t)n * TOTROW + pos) * 84 + j] = v;
}

// ---------------------------------------------------------------------------
extern "C" void kernel_launch(void* const* d_in, const int* in_sizes, int n_in,
                              void* d_out, int out_size, void* d_ws, size_t ws_size,
                              hipStream_t stream)
{
  (void)in_sizes; (void)n_in; (void)out_size; (void)ws_size;

  FPtrs F;
  for (int l = 0; l < 5; ++l) F.f[l] = (const float*)d_in[l];
  const float* cls_w  = (const float*)d_in[5];
  const float* cls_b  = (const float*)d_in[6];
  const float* cls_gw = (const float*)d_in[7];
  const float* cls_gb = (const float*)d_in[8];
  const float* box_w  = (const float*)d_in[9];
  const float* box_b  = (const float*)d_in[10];
  const float* box_gw = (const float*)d_in[11];
  const float* box_gb = (const float*)d_in[12];
  const float* score_w = (const float*)d_in[13];
  const float* score_b = (const float*)d_in[14];
  const float* pred_w  = (const float*)d_in[15];
  const float* pred_b  = (const float*)d_in[16];
  const float* ctr_w   = (const float*)d_in[17];
  const float* ctr_b   = (const float*)d_in[18];
  const float* scales  = (const float*)d_in[19];
  float* out = (float*)d_out;

  static const int Hs[5] = {100, 50, 25, 13, 7};
  static const int Ws[5] = {160, 80, 40, 20, 10};
  LvlP P;
  {
    static const int to[6] = {0, 45, 60, 66, 68, 69};   // 32x12 tiles
    static const int tX[5] = {5, 3, 2, 1, 1};
    static const int po[5] = {0, 16524, 20788, 21922, 22252};
    static const int pe[5] = {16524, 20788, 21922, 22252, 22360};
    static const int ro[6] = {0, 16000, 20000, 21000, 21260, 21330};
    for (int i = 0; i < 6; ++i) { P.tileoff[i] = to[i]; P.roff[i] = ro[i]; }
    for (int i = 0; i < 5; ++i) {
      P.tilesX[i] = tX[i]; P.H[i] = Hs[i]; P.W[i] = Ws[i];
      P.poff[i] = po[i]; P.pend[i] = pe[i];
      P.inv8HW[i] = 1.f / (8.f * Hs[i] * Ws[i]);
      P.strd[i] = (float)(8 << i);
    }
  }

  char* p = (char*)d_ws;
  auto alloc = [&](size_t bytes) {
    char* r = p;
    p += (bytes + 255) & ~(size_t)255;
    return r;
  };
  const size_t XPAD = (size_t)2 * PTOT * 256 * 2;
  const size_t YSZ  = (size_t)2 * TOTROW * 256 * 2;
  unsigned short* Xf  = (unsigned short*)alloc(XPAD);
  unsigned short* Xc  = (unsigned short*)alloc(XPAD);
  unsigned short* Xr  = (unsigned short*)alloc(XPAD);
  unsigned short* Yc  = (unsigned short*)alloc(YSZ);
  unsigned short* Yr  = (unsigned short*)alloc(YSZ);
  unsigned short* Yh  = (unsigned short*)alloc((size_t)4 * TOTROW * 128 * 2);
  unsigned short* wtC = (unsigned short*)alloc(4718592);
  unsigned short* wtR = (unsigned short*)alloc(4718592);
  unsigned short* wth = (unsigned short*)alloc(1179648);
  float* bh    = (float*)alloc(512);
  float* stats = (float*)alloc(4 * 5 * 4 * 32 * 2 * sizeof(float));

  setup_all<<<15001, 256, 0, stream>>>(cls_w, box_w, wtC, wtR,
                                       score_w, score_b, ctr_w, ctr_b,
                                       pred_w, pred_b, wth, bh,
                                       F, Xf, Xc, Xr, stats, P);

  for (int i = 0; i < 4; ++i) {
    const unsigned short* ic_ = (i == 0) ? Xf : Xc;
    const unsigned short* ir_ = (i == 0) ? Xf : Xr;
    float* st = stats + (size_t)i * 5 * 4 * 32 * 2;
    conv_mfma<<<dim3(2208), 256, 0, stream>>>(
        ic_, ir_, Yc, Yr,
        wtC + (size_t)i * 589824, wtR + (size_t)i * 589824,
        cls_b + i * 256, box_b + i * 256, st, P, 1, 256);
    gn_apply<<<dim3((TOTROW * 32 + 255) / 256, 4), 256, 0, stream>>>(
        Yc, Yr, Xc, Xr, st,
        cls_gw + i * 256, cls_gb + i * 256,
        box_gw + i * 256, box_gb + i * 256, P);
  }

  conv_mfma<<<dim3(1104), 256, 0, stream>>>(
      Xc, Xr, Yh, nullptr, wth, nullptr, bh, nullptr, nullptr, P, 2, 128);
  head_epi<<<dim3((TOTROW * 84 + 255) / 256, 2), 256, 0, stream>>>(
      Yh, out, scales, P);
}